// Round 2
// baseline (318.118 us; speedup 1.0000x reference)
//
#include <hip/hip_runtime.h>

// ContextualAttention: out[b,c,p] = sum_k K[b,k,c] * softmax_k( K[b,:,:] @ F[b,:,p] )
// K = rowwise-normalized (F^T + eps). Flash-style fusion, bf16 MFMA, f32 accum.

#define BATCH 8
#define CH 256
#define NPIX 4096
#define KT 64
#define WAVES 4
#define QTW 16
#define QTB (WAVES * QTW)
#define EPSV 1e-7f
#define L2E 1.4426950408889634f
#define RESCALE_TH 8.0f

using bf16x8 = __attribute__((ext_vector_type(8))) __bf16;
using bf16x4 = __attribute__((ext_vector_type(4))) __bf16;
using f32x4  = __attribute__((ext_vector_type(4))) float;

// ---------------- kernel 1: per-pixel inverse L2 norm of (F column + eps) ----
__global__ __launch_bounds__(256)
void ca_norms(const float* __restrict__ F, float* __restrict__ inv) {
  const int b = blockIdx.y;
  const int n = blockIdx.x * 256 + threadIdx.x;
  const float* Fb = F + (size_t)b * CH * NPIX + n;
  float s = 0.f;
#pragma unroll 8
  for (int c = 0; c < CH; ++c) {
    float v = Fb[(size_t)c * NPIX] + EPSV;
    s = fmaf(v, v, s);
  }
  inv[b * NPIX + n] = rsqrtf(s);
}

// ---------------- kernel 2: fused attention ---------------------------------
__global__ __launch_bounds__(256, 2)
void ca_attn(const float* __restrict__ F, const float* __restrict__ invn,
             float* __restrict__ Out) {
  // Kl[k][c]: GEMM1 A operand (rows = keys).  swizzle: c-index ^= (k&7)<<3
  // Kt[c][k]: GEMM2 A operand (rows = chans). swizzle: k-index ^= (c&7)<<3
  // Pl[w][q][k]: per-wave P buffer.           swizzle: k-index ^= (q&7)<<3
  __shared__ __align__(16) __bf16 Kl[KT][CH];           // 32 KB
  __shared__ __align__(16) __bf16 Kt[CH][KT];           // 32 KB
  __shared__ __align__(16) __bf16 Pl[WAVES][QTW][KT];   //  8 KB

  const int tid  = threadIdx.x;
  const int lane = tid & 63;
  const int w    = tid >> 6;
  const int b    = blockIdx.x;            // batch fastest -> one batch per XCD
  const int q0   = blockIdx.y * QTB;
  const int lq   = lane & 15;             // MFMA col (query)
  const int lg   = lane >> 4;             // lane group 0..3
  const int qg   = q0 + w * QTW + lq;     // this lane's query pixel

  const float* __restrict__ Fb   = F    + (size_t)b * CH * NPIX;
  const float* __restrict__ invb = invn + b * NPIX;

  // Q fragments (MFMA B operand), bf16, held in registers for the whole kernel.
  // B layout: lane holds B[k = lg*8+j within 32-chunk][col = lq]
  bf16x8 qf[8];
#pragma unroll
  for (int cf = 0; cf < 8; ++cf) {
#pragma unroll
    for (int j = 0; j < 8; ++j) {
      int c = cf * 32 + lg * 8 + j;
      qf[cf][j] = (__bf16)Fb[(size_t)c * NPIX + qg];
    }
  }

  const f32x4 zero = {0.f, 0.f, 0.f, 0.f};
  f32x4 oacc[16];
#pragma unroll
  for (int i = 0; i < 16; ++i) oacc[i] = zero;
  float m = -1e30f, l = 0.f;

  // staging roles
  const int iA  = tid & 15;   // float4 column index within key tile
  const int crA = tid >> 4;   // channel row (step 16)
  const int kB  = tid & 63;   // key index for Kl staging
  const int cqB = tid >> 6;   // channel quadrant for Kl staging

  for (int kt0 = 0; kt0 < NPIX; kt0 += KT) {
    // ---- stage Kt[c][k] = (F[c][k]+eps)*inv[k]  (coalesced float4 reads) ----
    {
      const float4 iv = *(const float4*)&invb[kt0 + 4 * iA];
#pragma unroll 8
      for (int rep = 0; rep < 16; ++rep) {
        int c = rep * 16 + crA;
        float4 v = *(const float4*)&Fb[(size_t)c * NPIX + kt0 + 4 * iA];
        bf16x4 o;
        o[0] = (__bf16)((v.x + EPSV) * iv.x);
        o[1] = (__bf16)((v.y + EPSV) * iv.y);
        o[2] = (__bf16)((v.z + EPSV) * iv.z);
        o[3] = (__bf16)((v.w + EPSV) * iv.w);
        *(bf16x4*)&Kt[c][(4 * iA) ^ ((c & 7) << 3)] = o;
      }
    }
    // ---- stage Kl[k][c]: gather 8 channels per key (coalesced across lanes) --
    {
      const float iv = invb[kt0 + kB];
#pragma unroll 2
      for (int rep = 0; rep < 8; ++rep) {
        int c0 = cqB * 8 + rep * 32;
        bf16x8 o;
#pragma unroll
        for (int j = 0; j < 8; ++j) {
          float v = Fb[(size_t)(c0 + j) * NPIX + kt0 + kB];
          o[j] = (__bf16)((v + EPSV) * iv);
        }
        *(bf16x8*)&Kl[kB][c0 ^ ((kB & 7) << 3)] = o;
      }
    }
    __syncthreads();

    // ---- GEMM1: S[k][q] = sum_c Kl[k][c] * Q[c][q] --------------------------
    f32x4 s[4];
#pragma unroll
    for (int ts = 0; ts < 4; ++ts) {
      s[ts] = zero;
      const int krow = ts * 16 + lq;     // A row = lane&15
#pragma unroll
      for (int cf = 0; cf < 8; ++cf) {
        bf16x8 a = *(const bf16x8*)&Kl[krow][(cf * 32 + lg * 8) ^ ((krow & 7) << 3)];
        s[ts] = __builtin_amdgcn_mfma_f32_16x16x32_bf16(a, qf[cf], s[ts], 0, 0, 0);
      }
    }

    // ---- online softmax over k (D layout: col=lq, row=lg*4+r) ---------------
    float pm = -3.0e38f;
#pragma unroll
    for (int ts = 0; ts < 4; ++ts)
#pragma unroll
      for (int r = 0; r < 4; ++r) pm = fmaxf(pm, s[ts][r]);
    pm = fmaxf(pm, __shfl_xor(pm, 16, 64));
    pm = fmaxf(pm, __shfl_xor(pm, 32, 64));

    if (!__all((pm - m) <= RESCALE_TH)) {     // defer-max (T13)
      float mn = fmaxf(m, pm);
      float sc = exp2f((m - mn) * L2E);
      l *= sc;
#pragma unroll
      for (int i = 0; i < 16; ++i) {
        oacc[i][0] *= sc; oacc[i][1] *= sc;
        oacc[i][2] *= sc; oacc[i][3] *= sc;
      }
      m = mn;
    }

    float lsum = 0.f;
#pragma unroll
    for (int ts = 0; ts < 4; ++ts) {
      bf16x4 pv;
#pragma unroll
      for (int r = 0; r < 4; ++r) {
        float p = exp2f((s[ts][r] - m) * L2E);
        lsum += p;
        pv[r] = (__bf16)p;
      }
      // rows ts*16 + lg*4 + [0..4) for column lq, swizzled by lq
      *(bf16x4*)&Pl[w][lq][(ts * 16 + lg * 4) ^ ((lq & 7) << 3)] = pv;
    }
    lsum += __shfl_xor(lsum, 16, 64);
    lsum += __shfl_xor(lsum, 32, 64);
    l += lsum;

    // ---- GEMM2: O[c][q] += sum_k Kt[c][k] * P[k][q] --------------------------
#pragma unroll
    for (int kf = 0; kf < 2; ++kf) {
      bf16x8 pf = *(const bf16x8*)&Pl[w][lq][(kf * 32 + lg * 8) ^ ((lq & 7) << 3)];
#pragma unroll
      for (int cs2 = 0; cs2 < 16; ++cs2) {
        const int c = cs2 * 16 + lq;     // A row = lane&15
        bf16x8 a = *(const bf16x8*)&Kt[c][(kf * 32 + lg * 8) ^ ((c & 7) << 3)];
        oacc[cs2] = __builtin_amdgcn_mfma_f32_16x16x32_bf16(a, pf, oacc[cs2], 0, 0, 0);
      }
    }
    __syncthreads();
  }

  // ---- epilogue: out = oacc / l --------------------------------------------
  const float rl = 1.0f / l;
  float* __restrict__ Ob = Out + (size_t)b * CH * NPIX;
#pragma unroll
  for (int cs2 = 0; cs2 < 16; ++cs2) {
#pragma unroll
    for (int r = 0; r < 4; ++r) {
      int c = cs2 * 16 + lg * 4 + r;
      Ob[(size_t)c * NPIX + qg] = oacc[cs2][r] * rl;
    }
  }
}

extern "C" void kernel_launch(void* const* d_in, const int* in_sizes, int n_in,
                              void* d_out, int out_size, void* d_ws, size_t ws_size,
                              hipStream_t stream) {
  const float* F = (const float*)d_in[0];
  float* out  = (float*)d_out;
  float* invn = (float*)d_ws;   // BATCH*NPIX floats = 128 KB

  ca_norms<<<dim3(NPIX / 256, BATCH), 256, 0, stream>>>(F, invn);
  ca_attn<<<dim3(BATCH, NPIX / QTB), 256, 0, stream>>>(F, invn, out);
}

// Round 3
// 233.956 us; speedup vs baseline: 1.3597x; 1.3597x over previous
//
#include <hip/hip_runtime.h>

// ContextualAttention: out[b,c,p] = sum_k K[b,k,c] * softmax_k( K[b,:,:] @ F[b,:,p] )
// K = rowwise-normalized (F^T + eps). Flash-style fusion, bf16 MFMA, f32 accum.
// Round 2: prep kernel writes pre-swizzled bf16 K images (both layouts) to ws;
//          attn kernel stages via linear global_load_lds, double-buffered KT=32.

#define BATCH 8
#define CH 256
#define NPIX 4096
#define EPSV 1e-7f
#define L2E 1.4426950408889634f
#define RESCALE_TH 8.0f

using bf16x8 = __attribute__((ext_vector_type(8))) __bf16;
using bf16x4 = __attribute__((ext_vector_type(4))) __bf16;
using f32x4  = __attribute__((ext_vector_type(4))) float;

__device__ __forceinline__ void gload16(const void* g, void* l) {
  __builtin_amdgcn_global_load_lds(
      (const __attribute__((address_space(1))) unsigned int*)g,
      (__attribute__((address_space(3))) unsigned int*)l, 16, 0, 0);
}

// ============================================================================
// Prep: per (batch, 32-key tile): compute inv-norms, normalized bf16 K, and
// write BOTH pre-swizzled LDS images to workspace:
//   KA[b][kt][32][256]: row k, 16B-unit u at u^(k&7)   (GEMM1 A-operand image)
//   KB[b][kt][256][32]: row c, 16B-unit v at v^(c&3)   (GEMM2 A-operand image)
// ============================================================================
__global__ __launch_bounds__(256)
void ca_prep(const float* __restrict__ F, __bf16* __restrict__ KA,
             __bf16* __restrict__ KB) {
  const int b   = blockIdx.y;
  const int kt  = blockIdx.x;          // 128 tiles of 32 keys
  const int kt0 = kt * 32;
  const int t   = threadIdx.x;
  const int k   = t & 31;
  const int h   = (t >> 5) & 1;
  const int w   = t >> 6;

  const float* __restrict__ Fb = F + (size_t)b * CH * NPIX;

  __shared__ float red[4][32];
  __shared__ float invk[32];
  __shared__ __align__(16) __bf16 T[32][264];   // +8 pad: 528B rows, 16B-aligned

  // load 32 elements (one per c in {w*2+h + 8*rep}), accumulate squared norm
  float fv[32];
  float ss = 0.f;
#pragma unroll
  for (int rep = 0; rep < 32; ++rep) {
    int c = rep * 8 + w * 2 + h;
    float v = Fb[(size_t)c * NPIX + kt0 + k] + EPSV;
    fv[rep] = v;
    ss = fmaf(v, v, ss);
  }
  ss += __shfl_xor(ss, 32, 64);
  if ((t & 32) == 0) red[w][k] = ss;
  __syncthreads();
  if (t < 32) invk[t] = rsqrtf(red[0][t] + red[1][t] + red[2][t] + red[3][t]);
  __syncthreads();
  const float iv = invk[k];
#pragma unroll
  for (int rep = 0; rep < 32; ++rep) {
    int c = rep * 8 + w * 2 + h;
    T[k][c] = (__bf16)(fv[rep] * iv);
  }
  __syncthreads();

  // emit KA image (32 rows x 32 units of 8 bf16), swizzled unit = u ^ (k&7)
  __bf16* KAp = KA + ((size_t)b * 128 + kt) * (32 * 256);
#pragma unroll
  for (int pass = 0; pass < 4; ++pass) {
    int kk = pass * 8 + (t >> 5);
    int u  = t & 31;
    bf16x8 v = *(const bf16x8*)&T[kk][u * 8];
    *(bf16x8*)&KAp[kk * 256 + ((u ^ (kk & 7)) * 8)] = v;
  }
  // emit KB image (256 rows x 4 units of 8 bf16), swizzled unit = v ^ (c&3)
  __bf16* KBp = KB + ((size_t)b * 128 + kt) * (256 * 32);
#pragma unroll
  for (int pass = 0; pass < 4; ++pass) {
    int c = pass * 64 + (t >> 2);
    int v = t & 3;
    bf16x8 o;
#pragma unroll
    for (int j = 0; j < 8; ++j) o[j] = T[v * 8 + j][c];
    *(bf16x8*)&KBp[c * 32 + ((v ^ (c & 3)) * 8)] = o;
  }
}

// ============================================================================
// Fused attention, KT=32, double-buffered DMA staging.
// Block = 256 threads (4 waves x 16 queries), grid = (batch, 64 q-tiles).
// ============================================================================
__device__ __forceinline__ void stage_tile(const char* sa, const char* sb,
                                           char* la, char* lb, int w, int lane) {
  const int go = w * 1024 + lane * 16;
  const int lo = w * 1024;              // wave-uniform LDS base; HW adds lane*16
#pragma unroll
  for (int i = 0; i < 4; ++i) gload16(sa + go + i * 4096, la + lo + i * 4096);
#pragma unroll
  for (int i = 0; i < 4; ++i) gload16(sb + go + i * 4096, lb + lo + i * 4096);
}

__global__ __launch_bounds__(256, 2)
void ca_attn2(const float* __restrict__ F, const __bf16* __restrict__ KA,
              const __bf16* __restrict__ KB, float* __restrict__ Out) {
  __shared__ __align__(16) __bf16 KAl[2][32][256];   // 32 KB
  __shared__ __align__(16) __bf16 KBl[2][256][32];   // 32 KB
  __shared__ __align__(16) __bf16 Pl[4][16][32];     //  4 KB

  const int tid  = threadIdx.x;
  const int lane = tid & 63;
  const int w    = tid >> 6;
  const int b    = blockIdx.x;              // batch fastest -> one batch per XCD
  const int q0   = blockIdx.y * 64;
  const int lq   = lane & 15;
  const int lg   = lane >> 4;
  const int qg   = q0 + w * 16 + lq;

  const float* __restrict__ Fb = F + (size_t)b * CH * NPIX;
  const char* KAb = (const char*)(KA + (size_t)b * (NPIX * CH));
  const char* KBb = (const char*)(KB + (size_t)b * (NPIX * CH));

  // kick off tile 0 staging before Q loads so DMA overlaps them
  stage_tile(KAb, KBb, (char*)&KAl[0][0][0], (char*)&KBl[0][0][0], w, lane);

  // Q fragments (MFMA B operand): qf[cf][j] = F[c = cf*32+lg*8+j][qg]
  bf16x8 qf[8];
#pragma unroll
  for (int cf = 0; cf < 8; ++cf) {
#pragma unroll
    for (int j = 0; j < 8; ++j) {
      int c = cf * 32 + lg * 8 + j;
      qf[cf][j] = (__bf16)Fb[(size_t)c * NPIX + qg];
    }
  }

  const f32x4 zero = {0.f, 0.f, 0.f, 0.f};
  f32x4 oacc[16];
#pragma unroll
  for (int i = 0; i < 16; ++i) oacc[i] = zero;
  float m = -1e30f, l = 0.f;

  int cur = 0;
  for (int t = 0; t < 128; ++t) {
    __syncthreads();   // vmcnt(0): tile t staged; all waves done with buf cur^1
    if (t + 1 < 128)
      stage_tile(KAb + (size_t)(t + 1) * 16384, KBb + (size_t)(t + 1) * 16384,
                 (char*)&KAl[cur ^ 1][0][0], (char*)&KBl[cur ^ 1][0][0], w, lane);

    // ---- GEMM1: S[k][q] = sum_c KA[k][c] * Q[c][q] ------------------------
    f32x4 s[2];
#pragma unroll
    for (int ts = 0; ts < 2; ++ts) {
      s[ts] = zero;
      const int krow = ts * 16 + lq;
#pragma unroll
      for (int cf = 0; cf < 8; ++cf) {
        int unit = (cf * 4 + lg) ^ (krow & 7);
        bf16x8 a = *(const bf16x8*)&KAl[cur][krow][unit * 8];
        s[ts] = __builtin_amdgcn_mfma_f32_16x16x32_bf16(a, qf[cf], s[ts], 0, 0, 0);
      }
    }

    // ---- online softmax over k (lane holds S[ts*16+lg*4+r][lq]) -----------
    float pm = -3.0e38f;
#pragma unroll
    for (int ts = 0; ts < 2; ++ts)
#pragma unroll
      for (int r = 0; r < 4; ++r) pm = fmaxf(pm, s[ts][r]);
    pm = fmaxf(pm, __shfl_xor(pm, 16, 64));
    pm = fmaxf(pm, __shfl_xor(pm, 32, 64));

    if (!__all((pm - m) <= RESCALE_TH)) {     // defer-max (T13)
      float mn = fmaxf(m, pm);
      float sc = exp2f((m - mn) * L2E);
      l *= sc;
#pragma unroll
      for (int i = 0; i < 16; ++i) {
        oacc[i][0] *= sc; oacc[i][1] *= sc;
        oacc[i][2] *= sc; oacc[i][3] *= sc;
      }
      m = mn;
    }

    float lsum = 0.f;
#pragma unroll
    for (int ts = 0; ts < 2; ++ts) {
      bf16x4 pv;
#pragma unroll
      for (int r = 0; r < 4; ++r) {
        float p = exp2f((s[ts][r] - m) * L2E);
        lsum += p;
        pv[r] = (__bf16)p;
      }
      *(bf16x4*)&Pl[w][lq][(ts * 16 + lg * 4) ^ ((lq & 3) << 3)] = pv;
    }
    lsum += __shfl_xor(lsum, 16, 64);
    lsum += __shfl_xor(lsum, 32, 64);
    l += lsum;

    // ---- GEMM2: O[c][q] += sum_k KB[c][k] * P[k][q] ------------------------
    bf16x8 pf = *(const bf16x8*)&Pl[w][lq][(lg * 8) ^ ((lq & 3) << 3)];
#pragma unroll
    for (int cs2 = 0; cs2 < 16; ++cs2) {
      const int c = cs2 * 16 + lq;
      int unit = lg ^ (c & 3);
      bf16x8 a = *(const bf16x8*)&KBl[cur][c][unit * 8];
      oacc[cs2] = __builtin_amdgcn_mfma_f32_16x16x32_bf16(a, pf, oacc[cs2], 0, 0, 0);
    }
    cur ^= 1;
  }

  // ---- epilogue: out = oacc / l --------------------------------------------
  const float rl = 1.0f / l;
  float* __restrict__ Ob = Out + (size_t)b * CH * NPIX;
#pragma unroll
  for (int cs2 = 0; cs2 < 16; ++cs2) {
#pragma unroll
    for (int r = 0; r < 4; ++r) {
      int c = cs2 * 16 + lg * 4 + r;
      Ob[(size_t)c * NPIX + qg] = oacc[cs2][r] * rl;
    }
  }
}

// ============================================================================
// Legacy round-1 path (fallback when ws is too small for the K images)
// ============================================================================
__global__ __launch_bounds__(256)
void ca_norms(const float* __restrict__ F, float* __restrict__ inv) {
  const int b = blockIdx.y;
  const int n = blockIdx.x * 256 + threadIdx.x;
  const float* Fb = F + (size_t)b * CH * NPIX + n;
  float s = 0.f;
#pragma unroll 8
  for (int c = 0; c < CH; ++c) {
    float v = Fb[(size_t)c * NPIX] + EPSV;
    s = fmaf(v, v, s);
  }
  inv[b * NPIX + n] = rsqrtf(s);
}

__global__ __launch_bounds__(256, 2)
void ca_attn(const float* __restrict__ F, const float* __restrict__ invn,
             float* __restrict__ Out) {
  __shared__ __align__(16) __bf16 Kl[64][CH];
  __shared__ __align__(16) __bf16 Kt[CH][64];
  __shared__ __align__(16) __bf16 Pl[4][16][64];

  const int tid  = threadIdx.x;
  const int lane = tid & 63;
  const int w    = tid >> 6;
  const int b    = blockIdx.x;
  const int q0   = blockIdx.y * 64;
  const int lq   = lane & 15;
  const int lg   = lane >> 4;
  const int qg   = q0 + w * 16 + lq;

  const float* __restrict__ Fb   = F    + (size_t)b * CH * NPIX;
  const float* __restrict__ invb = invn + b * NPIX;

  bf16x8 qf[8];
#pragma unroll
  for (int cf = 0; cf < 8; ++cf)
#pragma unroll
    for (int j = 0; j < 8; ++j) {
      int c = cf * 32 + lg * 8 + j;
      qf[cf][j] = (__bf16)Fb[(size_t)c * NPIX + qg];
    }

  const f32x4 zero = {0.f, 0.f, 0.f, 0.f};
  f32x4 oacc[16];
#pragma unroll
  for (int i = 0; i < 16; ++i) oacc[i] = zero;
  float m = -1e30f, l = 0.f;

  const int iA  = tid & 15;
  const int crA = tid >> 4;
  const int kB  = tid & 63;
  const int cqB = tid >> 6;

  for (int kt0 = 0; kt0 < NPIX; kt0 += 64) {
    {
      const float4 iv = *(const float4*)&invb[kt0 + 4 * iA];
#pragma unroll 8
      for (int rep = 0; rep < 16; ++rep) {
        int c = rep * 16 + crA;
        float4 v = *(const float4*)&Fb[(size_t)c * NPIX + kt0 + 4 * iA];
        bf16x4 o;
        o[0] = (__bf16)((v.x + EPSV) * iv.x);
        o[1] = (__bf16)((v.y + EPSV) * iv.y);
        o[2] = (__bf16)((v.z + EPSV) * iv.z);
        o[3] = (__bf16)((v.w + EPSV) * iv.w);
        *(bf16x4*)&Kt[c][(4 * iA) ^ ((c & 7) << 3)] = o;
      }
    }
    {
      const float iv = invb[kt0 + kB];
#pragma unroll 2
      for (int rep = 0; rep < 8; ++rep) {
        int c0 = cqB * 8 + rep * 32;
        bf16x8 o;
#pragma unroll
        for (int j = 0; j < 8; ++j) {
          float v = Fb[(size_t)(c0 + j) * NPIX + kt0 + kB];
          o[j] = (__bf16)((v + EPSV) * iv);
        }
        *(bf16x8*)&Kl[kB][c0 ^ ((kB & 7) << 3)] = o;
      }
    }
    __syncthreads();

    f32x4 s[4];
#pragma unroll
    for (int ts = 0; ts < 4; ++ts) {
      s[ts] = zero;
      const int krow = ts * 16 + lq;
#pragma unroll
      for (int cf = 0; cf < 8; ++cf) {
        bf16x8 a = *(const bf16x8*)&Kl[krow][(cf * 32 + lg * 8) ^ ((krow & 7) << 3)];
        s[ts] = __builtin_amdgcn_mfma_f32_16x16x32_bf16(a, qf[cf], s[ts], 0, 0, 0);
      }
    }

    float pm = -3.0e38f;
#pragma unroll
    for (int ts = 0; ts < 4; ++ts)
#pragma unroll
      for (int r = 0; r < 4; ++r) pm = fmaxf(pm, s[ts][r]);
    pm = fmaxf(pm, __shfl_xor(pm, 16, 64));
    pm = fmaxf(pm, __shfl_xor(pm, 32, 64));

    if (!__all((pm - m) <= RESCALE_TH)) {
      float mn = fmaxf(m, pm);
      float sc = exp2f((m - mn) * L2E);
      l *= sc;
#pragma unroll
      for (int i = 0; i < 16; ++i) {
        oacc[i][0] *= sc; oacc[i][1] *= sc;
        oacc[i][2] *= sc; oacc[i][3] *= sc;
      }
      m = mn;
    }

    float lsum = 0.f;
#pragma unroll
    for (int ts = 0; ts < 4; ++ts) {
      bf16x4 pv;
#pragma unroll
      for (int r = 0; r < 4; ++r) {
        float p = exp2f((s[ts][r] - m) * L2E);
        lsum += p;
        pv[r] = (__bf16)p;
      }
      *(bf16x4*)&Pl[w][lq][(ts * 16 + lg * 4) ^ ((lq & 7) << 3)] = pv;
    }
    lsum += __shfl_xor(lsum, 16, 64);
    lsum += __shfl_xor(lsum, 32, 64);
    l += lsum;

#pragma unroll
    for (int kf = 0; kf < 2; ++kf) {
      bf16x8 pf = *(const bf16x8*)&Pl[w][lq][(kf * 32 + lg * 8) ^ ((lq & 7) << 3)];
#pragma unroll
      for (int cs2 = 0; cs2 < 16; ++cs2) {
        const int c = cs2 * 16 + lq;
        bf16x8 a = *(const bf16x8*)&Kt[c][(kf * 32 + lg * 8) ^ ((c & 7) << 3)];
        oacc[cs2] = __builtin_amdgcn_mfma_f32_16x16x32_bf16(a, pf, oacc[cs2], 0, 0, 0);
      }
    }
    __syncthreads();
  }

  const float rl = 1.0f / l;
  float* __restrict__ Ob = Out + (size_t)b * CH * NPIX;
#pragma unroll
  for (int cs2 = 0; cs2 < 16; ++cs2)
#pragma unroll
    for (int r = 0; r < 4; ++r) {
      int c = cs2 * 16 + lg * 4 + r;
      Ob[(size_t)c * NPIX + qg] = oacc[cs2][r] * rl;
    }
}

// ============================================================================
extern "C" void kernel_launch(void* const* d_in, const int* in_sizes, int n_in,
                              void* d_out, int out_size, void* d_ws, size_t ws_size,
                              hipStream_t stream) {
  const float* F = (const float*)d_in[0];
  float* out = (float*)d_out;
  const size_t imgElems = (size_t)BATCH * NPIX * CH;           // 8.4M bf16 each

  if (ws_size >= 2 * imgElems * sizeof(__bf16)) {
    __bf16* KA = (__bf16*)d_ws;
    __bf16* KB = KA + imgElems;
    ca_prep<<<dim3(128, BATCH), 256, 0, stream>>>(F, KA, KB);
    ca_attn2<<<dim3(BATCH, 64), 256, 0, stream>>>(F, KA, KB, out);
  } else {
    float* invn = (float*)d_ws;   // 128 KB
    ca_norms<<<dim3(NPIX / 256, BATCH), 256, 0, stream>>>(F, invn);
    ca_attn<<<dim3(BATCH, 64), 256, 0, stream>>>(F, invn, out);
  }
}

// Round 4
// 188.062 us; speedup vs baseline: 1.6916x; 1.2440x over previous
//
#include <hip/hip_runtime.h>

// ContextualAttention: out[b,c,p] = sum_k K[b,k,c] * softmax_k( K[b,:,:] @ F[b,:,p] )
// K = rowwise-normalized (F^T + eps). Flash-style fusion, bf16 MFMA, f32 accum.
// Round 3: fixed softmax max m_q = ||F_q|| (Cauchy-Schwarz bound, exact shift) ->
//          no per-tile max/rescale/exchange; waves = (k-half x q-half), 32 q/wave
//          (2x A-frag reuse); conflict-free swizzles; 2 barriers/tile.

#define BATCH 8
#define CH 256
#define NPIX 4096
#define EPSV 1e-7f
#define L2E 1.4426950408889634f

using bf16x8 = __attribute__((ext_vector_type(8))) __bf16;
using bf16x4 = __attribute__((ext_vector_type(4))) __bf16;
using f32x4  = __attribute__((ext_vector_type(4))) float;

__device__ __forceinline__ void gload16(const void* g, void* l) {
  __builtin_amdgcn_global_load_lds(
      (const __attribute__((address_space(1))) unsigned int*)g,
      (__attribute__((address_space(3))) unsigned int*)l, 16, 0, 0);
}

__device__ __forceinline__ void lgkm_barrier() {
  asm volatile("s_waitcnt lgkmcnt(0)" ::: "memory");
  __builtin_amdgcn_s_barrier();
}

// ============================================================================
// Prep: per (batch, 32-key tile): inv-norms, normalized bf16 K, write BOTH
// pre-swizzled LDS images to workspace:
//   KA[b][kt][32 k][256 c]: 16B-unit u stored at u ^ (k&7)      (GEMM1 A image)
//   KB[b][kt][256 c][32 k]: 16B-unit v stored at v ^ ((c>>1)&3) (GEMM2 A image)
// ============================================================================
__global__ __launch_bounds__(256)
void ca_prep(const float* __restrict__ F, __bf16* __restrict__ KA,
             __bf16* __restrict__ KB) {
  const int b   = blockIdx.y;
  const int kt  = blockIdx.x;          // 128 tiles of 32 keys
  const int kt0 = kt * 32;
  const int t   = threadIdx.x;
  const int k   = t & 31;
  const int h   = (t >> 5) & 1;
  const int w   = t >> 6;

  const float* __restrict__ Fb = F + (size_t)b * CH * NPIX;

  __shared__ float red[4][32];
  __shared__ float invk[32];
  __shared__ __align__(16) __bf16 T[32][264];   // +8 pad

  float fv[32];
  float ss = 0.f;
#pragma unroll
  for (int rep = 0; rep < 32; ++rep) {
    int c = rep * 8 + w * 2 + h;
    float v = Fb[(size_t)c * NPIX + kt0 + k] + EPSV;
    fv[rep] = v;
    ss = fmaf(v, v, ss);
  }
  ss += __shfl_xor(ss, 32, 64);
  if ((t & 32) == 0) red[w][k] = ss;
  __syncthreads();
  if (t < 32) invk[t] = rsqrtf(red[0][t] + red[1][t] + red[2][t] + red[3][t]);
  __syncthreads();
  const float iv = invk[k];
#pragma unroll
  for (int rep = 0; rep < 32; ++rep) {
    int c = rep * 8 + w * 2 + h;
    T[k][c] = (__bf16)(fv[rep] * iv);
  }
  __syncthreads();

  // KA image
  __bf16* KAp = KA + ((size_t)b * 128 + kt) * (32 * 256);
#pragma unroll
  for (int pass = 0; pass < 4; ++pass) {
    int kk = pass * 8 + (t >> 5);
    int u  = t & 31;
    bf16x8 v = *(const bf16x8*)&T[kk][u * 8];
    *(bf16x8*)&KAp[kk * 256 + ((u ^ (kk & 7)) * 8)] = v;
  }
  // KB image
  __bf16* KBp = KB + ((size_t)b * 128 + kt) * (256 * 32);
#pragma unroll
  for (int pass = 0; pass < 4; ++pass) {
    int c = pass * 64 + (t >> 2);
    int v = t & 3;
    bf16x8 o;
#pragma unroll
    for (int j = 0; j < 8; ++j) o[j] = T[v * 8 + j][c];
    *(bf16x8*)&KBp[c * 32 + ((v ^ ((c >> 1) & 3)) * 8)] = o;
  }
}

// ============================================================================
// Fused attention. Block = 256 threads = 4 waves: wave w = (kh = w>>1, qh = w&1).
// Each wave: 16-key slice of GEMM1 + softmax for its 32 queries; 128-channel
// half of GEMM2 for its 32 queries. Grid = (8 batch, 64 q-tiles) = 512 blocks.
// ============================================================================
__global__ __launch_bounds__(256, 2)
void ca_attn3(const float* __restrict__ F, const __bf16* __restrict__ KA,
              const __bf16* __restrict__ KB, float* __restrict__ Out) {
  __shared__ __align__(16) __bf16 KAl[2][32][256];   // 32 KB
  __shared__ __align__(16) __bf16 KBl[2][256][32];   // 32 KB
  __shared__ __align__(16) __bf16 Pl[64 * 32];       //  4 KB, rows=q, swizzled
  __shared__ float lE[2][2][32];

  const int tid  = threadIdx.x;
  const int lane = tid & 63;
  const int w    = tid >> 6;
  const int kh   = w >> 1;
  const int qh   = w & 1;
  const int lq   = lane & 15;
  const int lg   = lane >> 4;
  const int b    = blockIdx.x;              // batch fastest -> one batch per XCD
  const int q0   = blockIdx.y * 64;
  const int qA   = q0 + qh * 32 + lq;       // query pixel, frag 0
  const int qB   = qA + 16;                 // query pixel, frag 1

  const float* __restrict__ Fb = F + (size_t)b * CH * NPIX;
  const char* KAb = (const char*)(KA + (size_t)b * (size_t)NPIX * CH);
  const char* KBb = (const char*)(KB + (size_t)b * (size_t)NPIX * CH);

  const int go = w * 1024 + lane * 16;   // per-lane global offset within 4KB chunk
  const int lo = w * 1024;               // wave-uniform LDS base

  // stage tile 0 (overlaps Q loads below)
#pragma unroll
  for (int i = 0; i < 4; ++i) gload16(KAb + go + i * 4096, (char*)KAl[0] + lo + i * 4096);
#pragma unroll
  for (int i = 0; i < 4; ++i) gload16(KBb + go + i * 4096, (char*)KBl[0] + lo + i * 4096);

  // Q fragments (MFMA B operand, raw F) + squared-norm partials for m_q
  bf16x8 qfA[8], qfB[8];
  float ssA = 0.f, ssB = 0.f;
#pragma unroll
  for (int cf = 0; cf < 8; ++cf) {
#pragma unroll
    for (int j = 0; j < 8; ++j) {
      int c = cf * 32 + lg * 8 + j;
      float va = Fb[(size_t)c * NPIX + qA];
      float vb = Fb[(size_t)c * NPIX + qB];
      qfA[cf][j] = (__bf16)va;
      qfB[cf][j] = (__bf16)vb;
      ssA = fmaf(va, va, ssA);
      ssB = fmaf(vb, vb, ssB);
    }
  }
  // sum the 4 lane-group partials (each covers disjoint 64 channels)
  ssA += __shfl_xor(ssA, 16, 64); ssA += __shfl_xor(ssA, 32, 64);
  ssB += __shfl_xor(ssB, 16, 64); ssB += __shfl_xor(ssB, 32, 64);
  // m_q = ||F_q||: provable upper bound of S[:,q] (rows of K are unit norm),
  // and equals the true max (diagonal) -> fixed softmax shift, no online max.
  const float mqA = sqrtf(ssA), mqB = sqrtf(ssB);

  const f32x4 zero = {0.f, 0.f, 0.f, 0.f};
  f32x4 oacc[8][2];
#pragma unroll
  for (int i = 0; i < 8; ++i) { oacc[i][0] = zero; oacc[i][1] = zero; }
  float lA = 0.f, lB = 0.f;

  const int krow = kh * 16 + lq;        // GEMM1 A row (wave's k-slice)
  const int ksw  = lq & 7;              // = krow & 7
  const int qla  = qh * 32 + lq;        // Pl row, frag 0
  const int qlb  = qla + 16;            // Pl row, frag 1
  const int rsw  = (lq >> 1) & 3;       // = (row>>1)&3 for all our Pl/KB rows
  const int pwOffA = qla * 32 + (((((kh << 1) | (lg >> 1)) ^ rsw) << 3) + ((lg & 1) << 2));
  const int pwOffB = qlb * 32 + (((((kh << 1) | (lg >> 1)) ^ rsw) << 3) + ((lg & 1) << 2));
  const int prOffA = qla * 32 + ((lg ^ rsw) << 3);
  const int prOffB = qlb * 32 + ((lg ^ rsw) << 3);

  int cur = 0;
  for (int t = 0; t < 128; ++t) {
    __syncthreads();   // drains vmcnt: tile t staged; all waves done with G2(t-1)
    if (t + 1 < 128) {
      const char* sa = KAb + (size_t)(t + 1) * 16384;
      const char* sb = KBb + (size_t)(t + 1) * 16384;
      char* la = (char*)KAl[cur ^ 1];
      char* lb = (char*)KBl[cur ^ 1];
#pragma unroll
      for (int i = 0; i < 4; ++i) gload16(sa + go + i * 4096, la + lo + i * 4096);
#pragma unroll
      for (int i = 0; i < 4; ++i) gload16(sb + go + i * 4096, lb + lo + i * 4096);
    }

    // ---- GEMM1: S[k][q] = sum_c KA[k][c] * Q[c][q]; A reused for both q-frags
    f32x4 s0 = zero, s1 = zero;
    __builtin_amdgcn_s_setprio(1);
#pragma unroll
    for (int cf = 0; cf < 8; ++cf) {
      bf16x8 a = *(const bf16x8*)&KAl[cur][krow][(((cf << 2) | lg) ^ ksw) << 3];
      s0 = __builtin_amdgcn_mfma_f32_16x16x32_bf16(a, qfA[cf], s0, 0, 0, 0);
      s1 = __builtin_amdgcn_mfma_f32_16x16x32_bf16(a, qfB[cf], s1, 0, 0, 0);
    }
    __builtin_amdgcn_s_setprio(0);

    // ---- softmax numerator with fixed shift; accumulate per-lane l partials
    bf16x4 pv0, pv1;
#pragma unroll
    for (int r = 0; r < 4; ++r) {
      float p0 = exp2f((s0[r] - mqA) * L2E);
      float p1 = exp2f((s1[r] - mqB) * L2E);
      lA += p0; lB += p1;
      pv0[r] = (__bf16)p0;
      pv1[r] = (__bf16)p1;
    }
    *(bf16x4*)&Pl[pwOffA] = pv0;
    *(bf16x4*)&Pl[pwOffB] = pv1;

    lgkm_barrier();   // P visible to all waves; staging loads stay in flight

    // ---- GEMM2: O[c][q] += sum_k KB[c][k] * P[k][q]; A reused for both q-frags
    bf16x8 pf0 = *(const bf16x8*)&Pl[prOffA];
    bf16x8 pf1 = *(const bf16x8*)&Pl[prOffB];
    __builtin_amdgcn_s_setprio(1);
#pragma unroll
    for (int ct = 0; ct < 8; ++ct) {
      const int c = kh * 128 + ct * 16 + lq;
      bf16x8 a = *(const bf16x8*)&KBl[cur][c][(lg ^ rsw) << 3];
      oacc[ct][0] = __builtin_amdgcn_mfma_f32_16x16x32_bf16(a, pf0, oacc[ct][0], 0, 0, 0);
      oacc[ct][1] = __builtin_amdgcn_mfma_f32_16x16x32_bf16(a, pf1, oacc[ct][1], 0, 0, 0);
    }
    __builtin_amdgcn_s_setprio(0);
    cur ^= 1;
  }

  // ---- final l: reduce over lane-groups, then combine k-halves via LDS ------
  lA += __shfl_xor(lA, 16, 64); lA += __shfl_xor(lA, 32, 64);
  lB += __shfl_xor(lB, 16, 64); lB += __shfl_xor(lB, 32, 64);
  if (lg == 0) lE[kh][qh][lq] = lA;
  if (lg == 1) lE[kh][qh][16 + lq] = lB;
  __syncthreads();
  const float rlA = 1.0f / (lA + lE[kh ^ 1][qh][lq]);
  const float rlB = 1.0f / (lB + lE[kh ^ 1][qh][16 + lq]);

  // ---- epilogue -------------------------------------------------------------
  float* __restrict__ Ob = Out + (size_t)b * CH * NPIX;
#pragma unroll
  for (int ct = 0; ct < 8; ++ct) {
#pragma unroll
    for (int r = 0; r < 4; ++r) {
      const int c = kh * 128 + ct * 16 + lg * 4 + r;
      Ob[(size_t)c * NPIX + qA] = oacc[ct][0][r] * rlA;
      Ob[(size_t)c * NPIX + qB] = oacc[ct][1][r] * rlB;
    }
  }
}

// ============================================================================
extern "C" void kernel_launch(void* const* d_in, const int* in_sizes, int n_in,
                              void* d_out, int out_size, void* d_ws, size_t ws_size,
                              hipStream_t stream) {
  const float* F = (const float*)d_in[0];
  float* out = (float*)d_out;
  const size_t imgElems = (size_t)BATCH * NPIX * CH;   // 8.4M bf16 per image

  __bf16* KAi = (__bf16*)d_ws;            // ws >= 33.6 MB (verified rounds 2-3)
  __bf16* KBi = KAi + imgElems;
  ca_prep<<<dim3(128, BATCH), 256, 0, stream>>>(F, KAi, KBi);
  ca_attn3<<<dim3(BATCH, 64), 256, 0, stream>>>(F, KAi, KBi, out);
}

// Round 5
// 167.560 us; speedup vs baseline: 1.8985x; 1.1224x over previous
//
#include <hip/hip_runtime.h>

// ContextualAttention: out[b,c,p] = sum_k K[b,k,c] * softmax_k( K[b,:,:] @ F[b,:,p] )
// K = rowwise-normalized (F^T + eps). Flash-style fusion, bf16 MFMA, f32 accum.
// Round 4: producer/consumer wave specialization (512-thr blocks, 8 waves):
//   waves 0-3: GEMM1 + softmax (fixed shift m_q = ||F_q||, exact) -> P dbuf
//   waves 4-7: GEMM2 with A-frags reg-staged direct from L2 (KB image, no LDS)
// One barrier per tile; LDS 41.5 KB; 16 waves/CU target.

#define BATCH 8
#define CH 256
#define NPIX 4096
#define EPSV 1e-7f
#define L2E 1.4426950408889634f

using bf16x8 = __attribute__((ext_vector_type(8))) __bf16;
using bf16x4 = __attribute__((ext_vector_type(4))) __bf16;
using f32x4  = __attribute__((ext_vector_type(4))) float;

__device__ __forceinline__ void gload16(const void* g, void* l) {
  __builtin_amdgcn_global_load_lds(
      (const __attribute__((address_space(1))) unsigned int*)g,
      (__attribute__((address_space(3))) unsigned int*)l, 16, 0, 0);
}

// ============================================================================
// Prep: per (batch, 32-key tile): inv-norms, normalized bf16 K, two images:
//   KA[b][kt][32 k][256 c]: 16B-unit u stored at u ^ (k&7)  (GEMM1 LDS image)
//   KB[b][kt][256 c][32 k]: plain layout                    (GEMM2 L2 image)
// Grid (BATCH, 128) so tile writes land on the batch's XCD.
// ============================================================================
__global__ __launch_bounds__(256)
void ca_prep(const float* __restrict__ F, __bf16* __restrict__ KA,
             __bf16* __restrict__ KB) {
  const int b   = blockIdx.x;
  const int kt  = blockIdx.y;          // 128 tiles of 32 keys
  const int kt0 = kt * 32;
  const int t   = threadIdx.x;
  const int k   = t & 31;
  const int h   = (t >> 5) & 1;
  const int w   = t >> 6;

  const float* __restrict__ Fb = F + (size_t)b * CH * NPIX;

  __shared__ float red[4][32];
  __shared__ float invk[32];
  __shared__ __align__(16) __bf16 T[32][264];   // +8 pad

  float fv[32];
  float ss = 0.f;
#pragma unroll
  for (int rep = 0; rep < 32; ++rep) {
    int c = rep * 8 + w * 2 + h;
    float v = Fb[(size_t)c * NPIX + kt0 + k] + EPSV;
    fv[rep] = v;
    ss = fmaf(v, v, ss);
  }
  ss += __shfl_xor(ss, 32, 64);
  if ((t & 32) == 0) red[w][k] = ss;
  __syncthreads();
  if (t < 32) invk[t] = rsqrtf(red[0][t] + red[1][t] + red[2][t] + red[3][t]);
  __syncthreads();
  const float iv = invk[k];
#pragma unroll
  for (int rep = 0; rep < 32; ++rep) {
    int c = rep * 8 + w * 2 + h;
    T[k][c] = (__bf16)(fv[rep] * iv);
  }
  __syncthreads();

  // KA image (swizzled for LDS ds_read)
  __bf16* KAp = KA + ((size_t)b * 128 + kt) * (32 * 256);
#pragma unroll
  for (int pass = 0; pass < 4; ++pass) {
    int kk = pass * 8 + (t >> 5);
    int u  = t & 31;
    bf16x8 v = *(const bf16x8*)&T[kk][u * 8];
    *(bf16x8*)&KAp[kk * 256 + ((u ^ (kk & 7)) * 8)] = v;
  }
  // KB image (plain [c][k] for direct coalesced global frag loads)
  __bf16* KBp = KB + ((size_t)b * 128 + kt) * (256 * 32);
#pragma unroll
  for (int pass = 0; pass < 4; ++pass) {
    int c = pass * 64 + (t >> 2);
    int v = t & 3;
    bf16x8 o;
#pragma unroll
    for (int j = 0; j < 8; ++j) o[j] = T[v * 8 + j][c];
    *(bf16x8*)&KBp[c * 32 + v * 8] = o;
  }
}

// ============================================================================
// Fused attention, producer/consumer. Grid (8 batch, 64 q-tiles), 512 threads.
// ============================================================================
__global__ __launch_bounds__(512, 4)
void ca_attn4(const float* __restrict__ F, const __bf16* __restrict__ KA,
              const __bf16* __restrict__ KB, float* __restrict__ Out) {
  __shared__ __align__(16) __bf16 KAl[2][32][256];   // 32 KB (dbuf KA tile)
  __shared__ __align__(16) __bf16 Pl[2][64][32];     //  8 KB (dbuf P)
  __shared__ float lE[2][64];                        // 512 B

  const int tid  = threadIdx.x;
  const int lane = tid & 63;
  const int w    = tid >> 6;            // 0..7
  const int lq   = lane & 15;
  const int lg   = lane >> 4;
  const int b    = blockIdx.x;          // batch fastest -> one batch per XCD
  const int q0   = blockIdx.y * 64;
  const int rsw  = (lq >> 1) & 3;       // shared P swizzle key

  const char* KAb = (const char*)(KA + (size_t)b * (size_t)NPIX * CH);
  const char* KBb = (const char*)(KB + (size_t)b * (size_t)NPIX * CH);

  if (w < 4) {
    // =================== producer: GEMM1 + softmax ========================
    const int kh = w >> 1, qh = w & 1;
    const int qA = q0 + qh * 32 + lq;
    const int qB = qA + 16;
    const float* __restrict__ Fb = F + (size_t)b * CH * NPIX;

    // stage KA(0): each producer wave covers 4 KB of the 16 KB tile
    {
      char* d = (char*)KAl[0];
#pragma unroll
      for (int j = 0; j < 4; ++j)
        gload16(KAb + w * 4096 + j * 1024 + lane * 16, d + w * 4096 + j * 1024);
    }

    // Q fragments (pre-scaled by L2E) + squared norms for the fixed shift
    bf16x8 qfA[8], qfB[8];
    float ssA = 0.f, ssB = 0.f;
#pragma unroll
    for (int cf = 0; cf < 8; ++cf) {
#pragma unroll
      for (int j = 0; j < 8; ++j) {
        int c = cf * 32 + lg * 8 + j;
        float va = Fb[(size_t)c * NPIX + qA];
        float vb = Fb[(size_t)c * NPIX + qB];
        qfA[cf][j] = (__bf16)(va * L2E);
        qfB[cf][j] = (__bf16)(vb * L2E);
        ssA = fmaf(va, va, ssA);
        ssB = fmaf(vb, vb, ssB);
      }
    }
    ssA += __shfl_xor(ssA, 16, 64); ssA += __shfl_xor(ssA, 32, 64);
    ssB += __shfl_xor(ssB, 16, 64); ssB += __shfl_xor(ssB, 32, 64);
    // m_q = ||F_q||: provable max of S[:,q] (K rows unit-norm), exact shift.
    const float mqA = sqrtf(ssA) * L2E, mqB = sqrtf(ssB) * L2E;

    float lA = 0.f, lB = 0.f;
    const int krow = kh * 16 + lq;
    const int ksw  = lq & 7;
    const int pu   = (kh << 1) | (lg >> 1);
    const int pwA  = (qh * 32 + lq) * 32 + (((pu ^ rsw) << 3) + ((lg & 1) << 2));
    const int pwB  = pwA + 16 * 32;

    __syncthreads();                                   // barrier 1

    const f32x4 zero = {0.f, 0.f, 0.f, 0.f};
    for (int i = 0; i < 128; ++i) {
      const int cb = i & 1;
      if (i < 127) {                                   // prefetch KA(i+1)
        const char* s = KAb + (size_t)(i + 1) * 16384;
        char* d = (char*)KAl[cb ^ 1];
#pragma unroll
        for (int j = 0; j < 4; ++j)
          gload16(s + w * 4096 + j * 1024 + lane * 16, d + w * 4096 + j * 1024);
      }

      f32x4 s0 = zero, s1 = zero;
      __builtin_amdgcn_s_setprio(1);
#pragma unroll
      for (int cf = 0; cf < 8; ++cf) {
        bf16x8 a = *(const bf16x8*)&KAl[cb][krow][(((cf << 2) | lg) ^ ksw) << 3];
        s0 = __builtin_amdgcn_mfma_f32_16x16x32_bf16(a, qfA[cf], s0, 0, 0, 0);
        s1 = __builtin_amdgcn_mfma_f32_16x16x32_bf16(a, qfB[cf], s1, 0, 0, 0);
      }
      __builtin_amdgcn_s_setprio(0);

      bf16x4 pv0, pv1;
#pragma unroll
      for (int r = 0; r < 4; ++r) {
        float p0 = exp2f(s0[r] - mqA);
        float p1 = exp2f(s1[r] - mqB);
        lA += p0; lB += p1;
        pv0[r] = (__bf16)p0;
        pv1[r] = (__bf16)p1;
      }
      *(bf16x4*)&Pl[cb][0][pwA] = pv0;
      *(bf16x4*)&Pl[cb][0][pwB] = pv1;

      __syncthreads();   // drains KA prefetch (vmcnt) + P writes (lgkm)
    }

    // final softmax denominators -> lE
    lA += __shfl_xor(lA, 16, 64); lA += __shfl_xor(lA, 32, 64);
    lB += __shfl_xor(lB, 16, 64); lB += __shfl_xor(lB, 32, 64);
    if (lg == 0) lE[kh][qh * 32 + lq] = lA;
    if (lg == 1) lE[kh][qh * 32 + 16 + lq] = lB;
    __syncthreads();                                   // barrier 130

  } else {
    // =================== consumer: GEMM2 ==================================
    const int cq = w - 4;
    const int c0 = cq * 64;
    const size_t fragBase = (size_t)(c0 + lq) * 64 + (size_t)lg * 16;
    const int pr0 = (0 * 16 + lq) * 32 + ((lg ^ rsw) << 3);
    const int pr1 = (1 * 16 + lq) * 32 + ((lg ^ rsw) << 3);
    const int pr2 = (2 * 16 + lq) * 32 + ((lg ^ rsw) << 3);
    const int pr3 = (3 * 16 + lq) * 32 + ((lg ^ rsw) << 3);

    const f32x4 zero = {0.f, 0.f, 0.f, 0.f};
    f32x4 oacc[4][4];
#pragma unroll
    for (int i = 0; i < 4; ++i)
#pragma unroll
      for (int j = 0; j < 4; ++j) oacc[i][j] = zero;

    __syncthreads();                                   // barrier 1

    for (int i = 0; i < 128; ++i) {
      if (i > 0) {
        const char* kbase = KBb + (size_t)(i - 1) * 16384 + fragBase;
        bf16x8 kb0 = *(const bf16x8*)(kbase);
        bf16x8 kb1 = *(const bf16x8*)(kbase + 1024);
        bf16x8 kb2 = *(const bf16x8*)(kbase + 2048);
        bf16x8 kb3 = *(const bf16x8*)(kbase + 3072);
        const __bf16* pb = &Pl[(i - 1) & 1][0][0];
        bf16x8 pf0 = *(const bf16x8*)&pb[pr0];
        bf16x8 pf1 = *(const bf16x8*)&pb[pr1];
        bf16x8 pf2 = *(const bf16x8*)&pb[pr2];
        bf16x8 pf3 = *(const bf16x8*)&pb[pr3];
        __builtin_amdgcn_s_setprio(1);
        oacc[0][0] = __builtin_amdgcn_mfma_f32_16x16x32_bf16(kb0, pf0, oacc[0][0], 0, 0, 0);
        oacc[0][1] = __builtin_amdgcn_mfma_f32_16x16x32_bf16(kb0, pf1, oacc[0][1], 0, 0, 0);
        oacc[0][2] = __builtin_amdgcn_mfma_f32_16x16x32_bf16(kb0, pf2, oacc[0][2], 0, 0, 0);
        oacc[0][3] = __builtin_amdgcn_mfma_f32_16x16x32_bf16(kb0, pf3, oacc[0][3], 0, 0, 0);
        oacc[1][0] = __builtin_amdgcn_mfma_f32_16x16x32_bf16(kb1, pf0, oacc[1][0], 0, 0, 0);
        oacc[1][1] = __builtin_amdgcn_mfma_f32_16x16x32_bf16(kb1, pf1, oacc[1][1], 0, 0, 0);
        oacc[1][2] = __builtin_amdgcn_mfma_f32_16x16x32_bf16(kb1, pf2, oacc[1][2], 0, 0, 0);
        oacc[1][3] = __builtin_amdgcn_mfma_f32_16x16x32_bf16(kb1, pf3, oacc[1][3], 0, 0, 0);
        oacc[2][0] = __builtin_amdgcn_mfma_f32_16x16x32_bf16(kb2, pf0, oacc[2][0], 0, 0, 0);
        oacc[2][1] = __builtin_amdgcn_mfma_f32_16x16x32_bf16(kb2, pf1, oacc[2][1], 0, 0, 0);
        oacc[2][2] = __builtin_amdgcn_mfma_f32_16x16x32_bf16(kb2, pf2, oacc[2][2], 0, 0, 0);
        oacc[2][3] = __builtin_amdgcn_mfma_f32_16x16x32_bf16(kb2, pf3, oacc[2][3], 0, 0, 0);
        oacc[3][0] = __builtin_amdgcn_mfma_f32_16x16x32_bf16(kb3, pf0, oacc[3][0], 0, 0, 0);
        oacc[3][1] = __builtin_amdgcn_mfma_f32_16x16x32_bf16(kb3, pf1, oacc[3][1], 0, 0, 0);
        oacc[3][2] = __builtin_amdgcn_mfma_f32_16x16x32_bf16(kb3, pf2, oacc[3][2], 0, 0, 0);
        oacc[3][3] = __builtin_amdgcn_mfma_f32_16x16x32_bf16(kb3, pf3, oacc[3][3], 0, 0, 0);
        __builtin_amdgcn_s_setprio(0);
      }
      __syncthreads();
    }

    // tile 127
    {
      const char* kbase = KBb + (size_t)127 * 16384 + fragBase;
      bf16x8 kb0 = *(const bf16x8*)(kbase);
      bf16x8 kb1 = *(const bf16x8*)(kbase + 1024);
      bf16x8 kb2 = *(const bf16x8*)(kbase + 2048);
      bf16x8 kb3 = *(const bf16x8*)(kbase + 3072);
      const __bf16* pb = &Pl[1][0][0];
      bf16x8 pf0 = *(const bf16x8*)&pb[pr0];
      bf16x8 pf1 = *(const bf16x8*)&pb[pr1];
      bf16x8 pf2 = *(const bf16x8*)&pb[pr2];
      bf16x8 pf3 = *(const bf16x8*)&pb[pr3];
      __builtin_amdgcn_s_setprio(1);
#pragma unroll
      for (int qt = 0; qt < 4; ++qt) {
        bf16x8 pf = qt == 0 ? pf0 : qt == 1 ? pf1 : qt == 2 ? pf2 : pf3;
        oacc[0][qt] = __builtin_amdgcn_mfma_f32_16x16x32_bf16(kb0, pf, oacc[0][qt], 0, 0, 0);
        oacc[1][qt] = __builtin_amdgcn_mfma_f32_16x16x32_bf16(kb1, pf, oacc[1][qt], 0, 0, 0);
        oacc[2][qt] = __builtin_amdgcn_mfma_f32_16x16x32_bf16(kb2, pf, oacc[2][qt], 0, 0, 0);
        oacc[3][qt] = __builtin_amdgcn_mfma_f32_16x16x32_bf16(kb3, pf, oacc[3][qt], 0, 0, 0);
      }
      __builtin_amdgcn_s_setprio(0);
    }
    __syncthreads();                                   // barrier 130

    // epilogue: normalize and store
    float rl0 = 1.0f / (lE[0][0 * 16 + lq] + lE[1][0 * 16 + lq]);
    float rl1 = 1.0f / (lE[0][1 * 16 + lq] + lE[1][1 * 16 + lq]);
    float rl2 = 1.0f / (lE[0][2 * 16 + lq] + lE[1][2 * 16 + lq]);
    float rl3 = 1.0f / (lE[0][3 * 16 + lq] + lE[1][3 * 16 + lq]);
    float* __restrict__ Ob = Out + (size_t)b * CH * NPIX;
#pragma unroll
    for (int ct = 0; ct < 4; ++ct) {
#pragma unroll
      for (int r = 0; r < 4; ++r) {
        const int c = c0 + ct * 16 + lg * 4 + r;
        float* orow = Ob + (size_t)c * NPIX + q0;
        orow[0 * 16 + lq] = oacc[ct][0][r] * rl0;
        orow[1 * 16 + lq] = oacc[ct][1][r] * rl1;
        orow[2 * 16 + lq] = oacc[ct][2][r] * rl2;
        orow[3 * 16 + lq] = oacc[ct][3][r] * rl3;
      }
    }
  }
}

// ============================================================================
extern "C" void kernel_launch(void* const* d_in, const int* in_sizes, int n_in,
                              void* d_out, int out_size, void* d_ws, size_t ws_size,
                              hipStream_t stream) {
  const float* F = (const float*)d_in[0];
  float* out = (float*)d_out;
  const size_t imgElems = (size_t)BATCH * NPIX * CH;   // 8.4M bf16 per image

  __bf16* KAi = (__bf16*)d_ws;            // ws >= 33.6 MB (verified rounds 2-4)
  __bf16* KBi = KAi + imgElems;
  ca_prep<<<dim3(BATCH, 128), 256, 0, stream>>>(F, KAi, KBi);
  ca_attn4<<<dim3(BATCH, 64), 512, 0, stream>>>(F, KAi, KBi, out);
}

// Round 6
// 166.448 us; speedup vs baseline: 1.9112x; 1.0067x over previous
//
#include <hip/hip_runtime.h>

// ContextualAttention: out[b,c,p] = sum_k K[b,k,c] * softmax_k( K[b,:,:] @ F[b,:,p] )
// K = rowwise-normalized (F^T + eps). Flash-style fusion, bf16 MFMA, f32 accum.
// Round 5: producer/consumer + deep pipeline:
//   consumer: KB frags reg-double-buffered, prefetched 1 phase ahead; raw
//             lgkm-only barriers keep global prefetch in flight (T3/T4).
//   producer: unchanged full-drain barriers (its DMA fills LDS read by peers).

#define BATCH 8
#define CH 256
#define NPIX 4096
#define EPSV 1e-7f
#define L2E 1.4426950408889634f

using bf16x8 = __attribute__((ext_vector_type(8))) __bf16;
using bf16x4 = __attribute__((ext_vector_type(4))) __bf16;
using f32x4  = __attribute__((ext_vector_type(4))) float;

__device__ __forceinline__ void gload16(const void* g, void* l) {
  __builtin_amdgcn_global_load_lds(
      (const __attribute__((address_space(1))) unsigned int*)g,
      (__attribute__((address_space(3))) unsigned int*)l, 16, 0, 0);
}

// producer barrier: full drain (its global_load_lds results are read by OTHER
// producer waves next phase; P writes must be visible).
__device__ __forceinline__ void barrier_full() {
  asm volatile("s_waitcnt vmcnt(0) lgkmcnt(0)\n"
               "s_barrier" ::: "memory");
}
// consumer barrier: LDS-only drain; its global->reg prefetch stays in flight.
__device__ __forceinline__ void barrier_lgkm() {
  asm volatile("s_waitcnt lgkmcnt(0)\n"
               "s_barrier" ::: "memory");
}

// ============================================================================
// Prep: per (batch, 32-key tile): inv-norms, normalized bf16 K, two images:
//   KA[b][kt][32 k][256 c]: 16B-unit u stored at u ^ (k&7)  (GEMM1 LDS image)
//   KB[b][kt][256 c][32 k]: plain layout                    (GEMM2 L2 image)
// ============================================================================
__global__ __launch_bounds__(256)
void ca_prep(const float* __restrict__ F, __bf16* __restrict__ KA,
             __bf16* __restrict__ KB) {
  const int b   = blockIdx.x;
  const int kt  = blockIdx.y;          // 128 tiles of 32 keys
  const int kt0 = kt * 32;
  const int t   = threadIdx.x;
  const int k   = t & 31;
  const int h   = (t >> 5) & 1;
  const int w   = t >> 6;

  const float* __restrict__ Fb = F + (size_t)b * CH * NPIX;

  __shared__ float red[4][32];
  __shared__ float invk[32];
  __shared__ __align__(16) __bf16 T[32][264];   // +8 pad

  float fv[32];
  float ss = 0.f;
#pragma unroll
  for (int rep = 0; rep < 32; ++rep) {
    int c = rep * 8 + w * 2 + h;
    float v = Fb[(size_t)c * NPIX + kt0 + k] + EPSV;
    fv[rep] = v;
    ss = fmaf(v, v, ss);
  }
  ss += __shfl_xor(ss, 32, 64);
  if ((t & 32) == 0) red[w][k] = ss;
  __syncthreads();
  if (t < 32) invk[t] = rsqrtf(red[0][t] + red[1][t] + red[2][t] + red[3][t]);
  __syncthreads();
  const float iv = invk[k];
#pragma unroll
  for (int rep = 0; rep < 32; ++rep) {
    int c = rep * 8 + w * 2 + h;
    T[k][c] = (__bf16)(fv[rep] * iv);
  }
  __syncthreads();

  // KA image (swizzled for LDS ds_read)
  __bf16* KAp = KA + ((size_t)b * 128 + kt) * (32 * 256);
#pragma unroll
  for (int pass = 0; pass < 4; ++pass) {
    int kk = pass * 8 + (t >> 5);
    int u  = t & 31;
    bf16x8 v = *(const bf16x8*)&T[kk][u * 8];
    *(bf16x8*)&KAp[kk * 256 + ((u ^ (kk & 7)) * 8)] = v;
  }
  // KB image (plain [c][k] for direct coalesced global frag loads)
  __bf16* KBp = KB + ((size_t)b * 128 + kt) * (256 * 32);
#pragma unroll
  for (int pass = 0; pass < 4; ++pass) {
    int c = pass * 64 + (t >> 2);
    int v = t & 3;
    bf16x8 o;
#pragma unroll
    for (int j = 0; j < 8; ++j) o[j] = T[v * 8 + j][c];
    *(bf16x8*)&KBp[c * 32 + v * 8] = o;
  }
}

// ============================================================================
// Fused attention, producer/consumer, deep pipeline.
// Grid (8 batch, 64 q-tiles), 512 threads = 8 waves.
// Phase p (p=0..127) lies between barrier #p+1 and #p+2 (130 barriers/role):
//   producer phase p: prefetch KA(p+1)->LDS, GEMM1(p), write P[p&1]
//   consumer phase p (p>=1): GEMM2 on tile p-1 with reg set S_{(p-1)&1},
//                            issue KB(p+1) loads into S_{(p+1)&1}
// ============================================================================
__global__ __launch_bounds__(512, 4)
void ca_attn5(const float* __restrict__ F, const __bf16* __restrict__ KA,
              const __bf16* __restrict__ KB, float* __restrict__ Out) {
  __shared__ __align__(16) __bf16 KAl[2][32][256];   // 32 KB (dbuf KA tile)
  __shared__ __align__(16) __bf16 Pl[2][64][32];     //  8 KB (dbuf P)
  __shared__ float lE[2][64];                        // 512 B

  const int tid  = threadIdx.x;
  const int lane = tid & 63;
  const int w    = tid >> 6;            // 0..7
  const int lq   = lane & 15;
  const int lg   = lane >> 4;
  const int b    = blockIdx.x;          // batch fastest -> one batch per XCD
  const int q0   = blockIdx.y * 64;
  const int rsw  = (lq >> 1) & 3;       // shared P swizzle key

  const char* KAb = (const char*)(KA + (size_t)b * (size_t)NPIX * CH);
  const char* KBb = (const char*)(KB + (size_t)b * (size_t)NPIX * CH);

  if (w < 4) {
    // =================== producer: GEMM1 + softmax ========================
    const int kh = w >> 1, qh = w & 1;
    const int qA = q0 + qh * 32 + lq;
    const int qB = qA + 16;
    const float* __restrict__ Fb = F + (size_t)b * CH * NPIX;

    // stage KA(0): each producer wave covers 4 KB of the 16 KB tile
    {
      char* d = (char*)KAl[0];
#pragma unroll
      for (int j = 0; j < 4; ++j)
        gload16(KAb + w * 4096 + j * 1024 + lane * 16, d + w * 4096 + j * 1024);
    }

    // Q fragments (pre-scaled by L2E) + squared norms for the fixed shift
    bf16x8 qfA[8], qfB[8];
    float ssA = 0.f, ssB = 0.f;
#pragma unroll
    for (int cf = 0; cf < 8; ++cf) {
#pragma unroll
      for (int j = 0; j < 8; ++j) {
        int c = cf * 32 + lg * 8 + j;
        float va = Fb[(size_t)c * NPIX + qA];
        float vb = Fb[(size_t)c * NPIX + qB];
        qfA[cf][j] = (__bf16)(va * L2E);
        qfB[cf][j] = (__bf16)(vb * L2E);
        ssA = fmaf(va, va, ssA);
        ssB = fmaf(vb, vb, ssB);
      }
    }
    ssA += __shfl_xor(ssA, 16, 64); ssA += __shfl_xor(ssA, 32, 64);
    ssB += __shfl_xor(ssB, 16, 64); ssB += __shfl_xor(ssB, 32, 64);
    // m_q = ||F_q||: provable max of S[:,q] (K rows unit-norm), exact shift.
    const float mqA = sqrtf(ssA) * L2E, mqB = sqrtf(ssB) * L2E;

    float lA = 0.f, lB = 0.f;
    const int krow = kh * 16 + lq;
    const int ksw  = lq & 7;
    const int pu   = (kh << 1) | (lg >> 1);
    const int pwA  = (qh * 32 + lq) * 32 + (((pu ^ rsw) << 3) + ((lg & 1) << 2));
    const int pwB  = pwA + 16 * 32;

    barrier_full();                                  // #1

    const f32x4 zero = {0.f, 0.f, 0.f, 0.f};
    const char* kanext = KAb + 16384;
    for (int i = 0; i < 128; ++i) {
      const int cb = i & 1;
      if (i < 127) {                                 // prefetch KA(i+1)
        char* d = (char*)KAl[cb ^ 1];
#pragma unroll
        for (int j = 0; j < 4; ++j)
          gload16(kanext + w * 4096 + j * 1024 + lane * 16, d + w * 4096 + j * 1024);
        kanext += 16384;
      }

      f32x4 s0 = zero, s1 = zero;
      __builtin_amdgcn_s_setprio(1);
#pragma unroll
      for (int cf = 0; cf < 8; ++cf) {
        bf16x8 a = *(const bf16x8*)&KAl[cb][krow][(((cf << 2) | lg) ^ ksw) << 3];
        s0 = __builtin_amdgcn_mfma_f32_16x16x32_bf16(a, qfA[cf], s0, 0, 0, 0);
        s1 = __builtin_amdgcn_mfma_f32_16x16x32_bf16(a, qfB[cf], s1, 0, 0, 0);
      }
      __builtin_amdgcn_s_setprio(0);

      bf16x4 pv0, pv1;
#pragma unroll
      for (int r = 0; r < 4; ++r) {
        float p0 = exp2f(s0[r] - mqA);
        float p1 = exp2f(s1[r] - mqB);
        lA += p0; lB += p1;
        pv0[r] = (__bf16)p0;
        pv1[r] = (__bf16)p1;
      }
      *(bf16x4*)&Pl[cb][0][pwA] = pv0;
      *(bf16x4*)&Pl[cb][0][pwB] = pv1;

      barrier_full();                                // #i+2  (drains KA DMA + P)
    }

    // phase 128: final softmax denominators -> lE
    lA += __shfl_xor(lA, 16, 64); lA += __shfl_xor(lA, 32, 64);
    lB += __shfl_xor(lB, 16, 64); lB += __shfl_xor(lB, 32, 64);
    if (lg == 0) lE[kh][qh * 32 + lq] = lA;
    if (lg == 1) lE[kh][qh * 32 + 16 + lq] = lB;
    barrier_full();                                  // #130

  } else {
    // =================== consumer: GEMM2 ==================================
    const int cq = w - 4;
    const int c0 = cq * 64;
    const size_t fragBase = (size_t)(c0 + lq) * 64 + (size_t)lg * 16;
    const int prBase = lq * 32 + ((lg ^ rsw) << 3);  // + j*512 for q-frag j

    const f32x4 zero = {0.f, 0.f, 0.f, 0.f};
    f32x4 oacc[4][4];
#pragma unroll
    for (int i = 0; i < 4; ++i)
#pragma unroll
      for (int j = 0; j < 4; ++j) oacc[i][j] = zero;

    bf16x8 a0, a1, a2, a3, b0, b1, b2, b3;   // KB frag reg double-buffer
    const char* kptr = KBb + fragBase;

#define LOAD_KB(R0, R1, R2, R3)                                              \
  do {                                                                       \
    R0 = *(const bf16x8*)(kptr);                                             \
    R1 = *(const bf16x8*)(kptr + 1024);                                      \
    R2 = *(const bf16x8*)(kptr + 2048);                                      \
    R3 = *(const bf16x8*)(kptr + 3072);                                      \
    kptr += 16384;                                                           \
  } while (0)

#define GEMM2_PHASE(K0, K1, K2, K3, PB)                                      \
  do {                                                                       \
    const __bf16* pb_ = &Pl[PB][0][0];                                       \
    bf16x8 pf0 = *(const bf16x8*)&pb_[prBase];                               \
    bf16x8 pf1 = *(const bf16x8*)&pb_[prBase + 16 * 32];                     \
    bf16x8 pf2 = *(const bf16x8*)&pb_[prBase + 32 * 32];                     \
    bf16x8 pf3 = *(const bf16x8*)&pb_[prBase + 48 * 32];                     \
    __builtin_amdgcn_s_setprio(1);                                           \
    oacc[0][0] = __builtin_amdgcn_mfma_f32_16x16x32_bf16(K0, pf0, oacc[0][0], 0, 0, 0); \
    oacc[0][1] = __builtin_amdgcn_mfma_f32_16x16x32_bf16(K0, pf1, oacc[0][1], 0, 0, 0); \
    oacc[0][2] = __builtin_amdgcn_mfma_f32_16x16x32_bf16(K0, pf2, oacc[0][2], 0, 0, 0); \
    oacc[0][3] = __builtin_amdgcn_mfma_f32_16x16x32_bf16(K0, pf3, oacc[0][3], 0, 0, 0); \
    oacc[1][0] = __builtin_amdgcn_mfma_f32_16x16x32_bf16(K1, pf0, oacc[1][0], 0, 0, 0); \
    oacc[1][1] = __builtin_amdgcn_mfma_f32_16x16x32_bf16(K1, pf1, oacc[1][1], 0, 0, 0); \
    oacc[1][2] = __builtin_amdgcn_mfma_f32_16x16x32_bf16(K1, pf2, oacc[1][2], 0, 0, 0); \
    oacc[1][3] = __builtin_amdgcn_mfma_f32_16x16x32_bf16(K1, pf3, oacc[1][3], 0, 0, 0); \
    oacc[2][0] = __builtin_amdgcn_mfma_f32_16x16x32_bf16(K2, pf0, oacc[2][0], 0, 0, 0); \
    oacc[2][1] = __builtin_amdgcn_mfma_f32_16x16x32_bf16(K2, pf1, oacc[2][1], 0, 0, 0); \
    oacc[2][2] = __builtin_amdgcn_mfma_f32_16x16x32_bf16(K2, pf2, oacc[2][2], 0, 0, 0); \
    oacc[2][3] = __builtin_amdgcn_mfma_f32_16x16x32_bf16(K2, pf3, oacc[2][3], 0, 0, 0); \
    oacc[3][0] = __builtin_amdgcn_mfma_f32_16x16x32_bf16(K3, pf0, oacc[3][0], 0, 0, 0); \
    oacc[3][1] = __builtin_amdgcn_mfma_f32_16x16x32_bf16(K3, pf1, oacc[3][1], 0, 0, 0); \
    oacc[3][2] = __builtin_amdgcn_mfma_f32_16x16x32_bf16(K3, pf2, oacc[3][2], 0, 0, 0); \
    oacc[3][3] = __builtin_amdgcn_mfma_f32_16x16x32_bf16(K3, pf3, oacc[3][3], 0, 0, 0); \
    __builtin_amdgcn_s_setprio(0);                                           \
  } while (0)

    LOAD_KB(a0, a1, a2, a3);                         // kb(0) -> A
    barrier_lgkm();                                  // #1
    LOAD_KB(b0, b1, b2, b3);                         // phase 0: kb(1) -> B
    barrier_lgkm();                                  // #2

    for (int ii = 0; ii < 64; ++ii) {
      // phase 2ii+1: tile 2ii with set A, P[0]
      GEMM2_PHASE(a0, a1, a2, a3, 0);
      if (ii < 63) LOAD_KB(a0, a1, a2, a3);          // kb(2ii+2) -> A
      barrier_lgkm();                                // #2ii+3
      // phase 2ii+2: tile 2ii+1 with set B, P[1]
      GEMM2_PHASE(b0, b1, b2, b3, 1);
      if (ii < 63) LOAD_KB(b0, b1, b2, b3);          // kb(2ii+3) -> B
      barrier_lgkm();                                // #2ii+4
    }
#undef LOAD_KB
#undef GEMM2_PHASE

    // epilogue: normalize and store (after barrier #130; lE published)
    float rl0 = 1.0f / (lE[0][0 * 16 + lq] + lE[1][0 * 16 + lq]);
    float rl1 = 1.0f / (lE[0][1 * 16 + lq] + lE[1][1 * 16 + lq]);
    float rl2 = 1.0f / (lE[0][2 * 16 + lq] + lE[1][2 * 16 + lq]);
    float rl3 = 1.0f / (lE[0][3 * 16 + lq] + lE[1][3 * 16 + lq]);
    float* __restrict__ Ob = Out + (size_t)b * CH * NPIX;
#pragma unroll
    for (int ct = 0; ct < 4; ++ct) {
#pragma unroll
      for (int r = 0; r < 4; ++r) {
        const int c = c0 + ct * 16 + lg * 4 + r;
        float* orow = Ob + (size_t)c * NPIX + q0;
        orow[0 * 16 + lq] = oacc[ct][0][r] * rl0;
        orow[1 * 16 + lq] = oacc[ct][1][r] * rl1;
        orow[2 * 16 + lq] = oacc[ct][2][r] * rl2;
        orow[3 * 16 + lq] = oacc[ct][3][r] * rl3;
      }
    }
  }
}

// ============================================================================
extern "C" void kernel_launch(void* const* d_in, const int* in_sizes, int n_in,
                              void* d_out, int out_size, void* d_ws, size_t ws_size,
                              hipStream_t stream) {
  const float* F = (const float*)d_in[0];
  float* out = (float*)d_out;
  const size_t imgElems = (size_t)BATCH * NPIX * CH;   // 8.4M bf16 per image

  __bf16* KAi = (__bf16*)d_ws;            // ws >= 33.6 MB (verified rounds 2-4)
  __bf16* KBi = KAi + imgElems;
  ca_prep<<<dim3(BATCH, 128), 256, 0, stream>>>(F, KAi, KBi);
  ca_attn5<<<dim3(BATCH, 64), 512, 0, stream>>>(F, KAi, KBi, out);
}